// Round 2
// baseline (335.679 us; speedup 1.0000x reference)
//
#include <hip/hip_runtime.h>

// out[b,c,h,w] = block_switch[h/8, w/8] ? -1.0f : image[b,c,h,w]
// image: [64, 3, 512, 512] fp32 ; block_switch: [64, 64] (bool -> int32 per harness)
//
// One thread per 8-float (32 B) group == exactly one mask block along w.
// elem = idx*8 ; w>>3 = idx & 63 ; h>>3 = (idx>>9) & 63  (W = 512 = 2^9, H = 512)
// -> mask index = ((idx>>9) & 63)*64 + (idx & 63), pure shifts/ands.
//
// Image/out are streaming (zero reuse) -> nontemporal loads/stores (nt flag),
// keeping L2 for the 16 KB mask. Conditional load skips fetch of masked blocks.

typedef float v4f __attribute__((ext_vector_type(4)));

__global__ __launch_bounds__(256) void grid_crop_kernel(
    const v4f* __restrict__ img,
    const int* __restrict__ mask,
    v4f* __restrict__ out,
    int n8)                              // number of 8-float groups
{
    int idx = blockIdx.x * blockDim.x + threadIdx.x;
    if (idx >= n8) return;

    int mi = (((idx >> 9) & 63) << 6) | (idx & 63);
    int m  = mask[mi];

    int base = idx << 1;                 // float4 index
    v4f a, b;
    if (m) {
        a = (v4f){-1.0f, -1.0f, -1.0f, -1.0f};
        b = a;
    } else {
        a = __builtin_nontemporal_load(&img[base]);
        b = __builtin_nontemporal_load(&img[base + 1]);
    }
    __builtin_nontemporal_store(a, &out[base]);
    __builtin_nontemporal_store(b, &out[base + 1]);
}

extern "C" void kernel_launch(void* const* d_in, const int* in_sizes, int n_in,
                              void* d_out, int out_size, void* d_ws, size_t ws_size,
                              hipStream_t stream) {
    const v4f* img  = (const v4f*)d_in[0];
    const int* mask = (const int*)d_in[1];
    v4f*       out  = (v4f*)d_out;

    int n8 = out_size >> 3;              // 64*3*512*512 / 8 = 6,291,456
    int block = 256;
    int grid = (n8 + block - 1) / block; // 24,576 blocks

    grid_crop_kernel<<<grid, block, 0, stream>>>(img, mask, out, n8);
}